// Round 2
// baseline (929.926 us; speedup 1.0000x reference)
//
#include <hip/hip_runtime.h>
#include <cstdint>
#include <cstddef>

typedef unsigned short u16;
typedef __bf16 bf16x8 __attribute__((ext_vector_type(8)));
typedef float f32x4 __attribute__((ext_vector_type(4)));
typedef u16 u16x8 __attribute__((ext_vector_type(8)));

#define B_DIM 4096
#define H_DIM 2048
#define BH 8388608  // B_DIM * H_DIM

__device__ __forceinline__ float b2f(u16 x) {
  union { uint32_t u; float f; } v;
  v.u = ((uint32_t)x) << 16;
  return v.f;
}
__device__ __forceinline__ u16 f2b(float f) {
  union { float f; uint32_t u; } v;
  v.f = f;
  uint32_t r = v.u + 0x7FFFu + ((v.u >> 16) & 1u);
  return (u16)(r >> 16);
}
__device__ __forceinline__ float sigm(float x) { return 1.0f / (1.0f + __expf(-x)); }

typedef __attribute__((address_space(1))) void gv_t;
typedef __attribute__((address_space(3))) void lv_t;
__device__ __forceinline__ void g2lds16(const void* g, void* l) {
  __builtin_amdgcn_global_load_lds((gv_t*)g, (lv_t*)l, 16, 0, 0);
}

// ---------------- fp32 -> bf16 activation convert ----------------
struct CvtParams { const float* src[3]; u16* dst[3]; };

__global__ __launch_bounds__(256) void cvt_k(CvtParams p) {
  const float* __restrict__ s = p.src[blockIdx.y];
  u16* __restrict__ d = p.dst[blockIdx.y];
  size_t idx = ((size_t)blockIdx.x * 256 + threadIdx.x) * 8;
  float4 a = *(const float4*)(s + idx);
  float4 b = *(const float4*)(s + idx + 4);
  u16x8 o;
  o[0] = f2b(a.x); o[1] = f2b(a.y); o[2] = f2b(a.z); o[3] = f2b(a.w);
  o[4] = f2b(b.x); o[5] = f2b(b.y); o[6] = f2b(b.z); o[7] = f2b(b.w);
  *(u16x8*)(d + idx) = o;
}

// ---------------- weight transpose+convert: Wt[n][k] = bf16(W[k][n]) ----------------
struct TransParams {
  const float* src[13];
  u16* dst[13];
  int dstride[13];
};

__global__ __launch_bounds__(256) void transpose_k(TransParams p) {
  __shared__ u16 lds[64][72];  // pitch 72 breaks bank aliasing; rows 16B-aligned
  const int mat = blockIdx.z;
  const float* __restrict__ src = p.src[mat];
  u16* __restrict__ dst = p.dst[mat];
  const int dstride = p.dstride[mat];
  const int tk = blockIdx.y * 64;  // src row (k) base
  const int tn = blockIdx.x * 64;  // src col (n) base
  const int t = threadIdx.x;
  const int lr = t >> 3;        // 0..31
  const int lc = (t & 7) * 8;   // 0..56 step 8
#pragma unroll
  for (int half = 0; half < 2; half++) {
    int r = lr + half * 32;
    const float4* g = (const float4*)(src + (size_t)(tk + r) * 2048 + tn + lc);
    float4 a = g[0], b = g[1];
    u16x8 t8;
    t8[0] = f2b(a.x); t8[1] = f2b(a.y); t8[2] = f2b(a.z); t8[3] = f2b(a.w);
    t8[4] = f2b(b.x); t8[5] = f2b(b.y); t8[6] = f2b(b.z); t8[7] = f2b(b.w);
    *(u16x8*)&lds[r][lc] = t8;
  }
  __syncthreads();
#pragma unroll
  for (int half = 0; half < 2; half++) {
    int n = lr + half * 32;
    u16x8 tmp;
#pragma unroll
    for (int j = 0; j < 8; j++) tmp[j] = lds[lc + j][n];
    *(u16x8*)(dst + (size_t)(tn + n) * dstride + tk + lc) = tmp;
  }
}

// ---------------- GEMM: C[4096,2048](bf16) (+)= sum_seg A_seg[4096,2048] @ Wt_seg^T ----------------
// Wt is [2048 n][Ktot k] row-major (k contiguous), Ktot = nseg*2048. A is bf16.
struct GemmDesc {
  const u16* A0; const u16* A1; const u16* A2;
  const u16* Wt; u16* C; int nseg; int addin;
};
struct GemmParams { GemmDesc d[5]; };

__global__ __launch_bounds__(256) void gemm_multi(GemmParams p) {
  const GemmDesc d = p.d[blockIdx.z];
  const int nseg = d.nseg;
  const long Ktot = (long)nseg * 2048;

  __shared__ u16 ldsA[128 * 32];  // [row][k]
  __shared__ u16 ldsB[128 * 32];  // [n][k]

  const int t = threadIdx.x;
  const int wave = t >> 6, lane = t & 63;
  const int m0 = blockIdx.y * 128, n0 = blockIdx.x * 128;

  // staging: wave w loads rows [w*32, w*32+32); lane -> (row = lane>>2, kchunk = (lane&3)*8)
  const int sr = lane >> 2;
  const int sc = (lane & 3) * 8;
  u16* lA0 = &ldsA[wave * 1024];
  u16* lA1 = lA0 + 512;
  u16* lB0 = &ldsB[wave * 1024];
  u16* lB1 = lB0 + 512;
  const size_t rA0 = (size_t)(m0 + wave * 32 + sr);
  const size_t rB0 = (size_t)(n0 + wave * 32 + sr);

  // fragment addressing (16x16x32): A[m=lane&15][k=quad*8+j], B likewise (B^T trick)
  const int fm = lane & 15, fk = (lane >> 4) * 8;
  const int wm = (wave >> 1) * 64, wn = (wave & 1) * 64;

  f32x4 acc[4][4];
#pragma unroll
  for (int i = 0; i < 4; i++)
#pragma unroll
    for (int j = 0; j < 4; j++) acc[i][j] = (f32x4)0.0f;

  for (int seg = 0; seg < nseg; ++seg) {
    const u16* As = (seg == 0) ? d.A0 : ((seg == 1) ? d.A1 : d.A2);
    const u16* pA0 = As + rA0 * 2048 + sc;
    const u16* pA1 = pA0 + 16 * 2048;
    const u16* pB0 = d.Wt + rB0 * Ktot + (size_t)seg * 2048 + sc;
    const u16* pB1 = pB0 + 16 * Ktot;
    for (int kk = 0; kk < 2048; kk += 32) {
      __syncthreads();  // previous tile's LDS reads done
      g2lds16(pA0, lA0);
      g2lds16(pA1, lA1);
      g2lds16(pB0, lB0);
      g2lds16(pB1, lB1);
      __syncthreads();  // drains vmcnt(0): staged data visible
      bf16x8 af[4], bfr[4];
#pragma unroll
      for (int i = 0; i < 4; i++)
        af[i] = *(const bf16x8*)&ldsA[(wm + i * 16 + fm) * 32 + fk];
#pragma unroll
      for (int j = 0; j < 4; j++)
        bfr[j] = *(const bf16x8*)&ldsB[(wn + j * 16 + fm) * 32 + fk];
#pragma unroll
      for (int i = 0; i < 4; i++)
#pragma unroll
        for (int j = 0; j < 4; j++)
          acc[i][j] = __builtin_amdgcn_mfma_f32_16x16x32_bf16(af[i], bfr[j], acc[i][j], 0, 0, 0);
      pA0 += 32; pA1 += 32; pB0 += 32; pB1 += 32;
    }
  }

  // epilogue: C/D layout col=lane&15, row=quad*4+r
  const int quad = lane >> 4;
#pragma unroll
  for (int i = 0; i < 4; i++) {
#pragma unroll
    for (int j = 0; j < 4; j++) {
#pragma unroll
      for (int r = 0; r < 4; r++) {
        size_t row = (size_t)(m0 + wm + i * 16 + quad * 4 + r);
        size_t col = (size_t)(n0 + wn + j * 16 + fm);
        size_t cidx = row * 2048 + col;
        float v = acc[i][j][r];
        if (d.addin) v += b2f(d.C[cidx]);
        d.C[cidx] = f2b(v);
      }
    }
  }
}

// ---------------- elementwise 1: gates -> c; stash bf16(c), bf16(tanh c) in-place ----------------
__global__ __launch_bounds__(256) void ew1_k(
    u16* __restrict__ zi, const u16* __restrict__ zf, u16* __restrict__ zg,
    const float* __restrict__ cprev, const float* __restrict__ bi,
    const float* __restrict__ bff, const float* __restrict__ bg,
    float* __restrict__ c_out) {
  size_t idx = ((size_t)blockIdx.x * 256 + threadIdx.x) * 8;
  int col = (int)(idx & (H_DIM - 1));
  u16x8 vzi = *(const u16x8*)(zi + idx);
  u16x8 vzf = *(const u16x8*)(zf + idx);
  u16x8 vzg = *(const u16x8*)(zg + idx);
  float4 cp0 = *(const float4*)(cprev + idx);
  float4 cp1 = *(const float4*)(cprev + idx + 4);
  float4 bi0 = *(const float4*)(bi + col), bi1 = *(const float4*)(bi + col + 4);
  float4 bf0 = *(const float4*)(bff + col), bf1 = *(const float4*)(bff + col + 4);
  float4 bg0 = *(const float4*)(bg + col), bg1 = *(const float4*)(bg + col + 4);
  float cpv[8] = {cp0.x, cp0.y, cp0.z, cp0.w, cp1.x, cp1.y, cp1.z, cp1.w};
  float biv[8] = {bi0.x, bi0.y, bi0.z, bi0.w, bi1.x, bi1.y, bi1.z, bi1.w};
  float bfv[8] = {bf0.x, bf0.y, bf0.z, bf0.w, bf1.x, bf1.y, bf1.z, bf1.w};
  float bgv[8] = {bg0.x, bg0.y, bg0.z, bg0.w, bg1.x, bg1.y, bg1.z, bg1.w};
  float cv[8], tcv[8];
#pragma unroll
  for (int e = 0; e < 8; e++) {
    float iv = b2f(vzi[e]) + biv[e];
    float fv = b2f(vzf[e]) + bfv[e];
    float gv = b2f(vzg[e]) + bgv[e];
    float c = sigm(fv) * cpv[e] + sigm(iv) * tanhf(gv);
    cv[e] = c;
    tcv[e] = tanhf(c);
  }
  u16x8 cb8, tc8;
#pragma unroll
  for (int e = 0; e < 8; e++) { cb8[e] = f2b(cv[e]); tc8[e] = f2b(tcv[e]); }
  *(u16x8*)(zi + idx) = cb8;   // bf16(c) for c @ w_co   (same elements this thread read)
  *(u16x8*)(zg + idx) = tc8;   // bf16(tanh c) for tanh(c) @ w_c
  float4 c0 = {cv[0], cv[1], cv[2], cv[3]}, c1 = {cv[4], cv[5], cv[6], cv[7]};
  *(float4*)(c_out + idx) = c0;
  *(float4*)(c_out + idx + 4) = c1;
}

// ---------------- elementwise 2: h = tanh(zo') * zr' ----------------
__global__ __launch_bounds__(256) void ew2_k(
    const u16* __restrict__ zo, const u16* __restrict__ zr,
    const float* __restrict__ bo, float* __restrict__ h_out) {
  size_t idx = ((size_t)blockIdx.x * 256 + threadIdx.x) * 8;
  int col = (int)(idx & (H_DIM - 1));
  u16x8 vzo = *(const u16x8*)(zo + idx);
  u16x8 vzr = *(const u16x8*)(zr + idx);
  float4 bo0 = *(const float4*)(bo + col), bo1 = *(const float4*)(bo + col + 4);
  float bov[8] = {bo0.x, bo0.y, bo0.z, bo0.w, bo1.x, bo1.y, bo1.z, bo1.w};
  float hv[8];
#pragma unroll
  for (int e = 0; e < 8; e++) {
    float ov = b2f(vzo[e]) + bov[e];
    hv[e] = tanhf(ov) * b2f(vzr[e]);
  }
  float4 h0 = {hv[0], hv[1], hv[2], hv[3]}, h1 = {hv[4], hv[5], hv[6], hv[7]};
  *(float4*)(h_out + idx) = h0;
  *(float4*)(h_out + idx + 4) = h1;
}

// ---------------- launch ----------------
extern "C" void kernel_launch(void* const* d_in, const int* in_sizes, int n_in,
                              void* d_out, int out_size, void* d_ws, size_t ws_size,
                              hipStream_t stream) {
  const float* input_ = (const float*)d_in[0];
  const float* h_prev = (const float*)d_in[1];
  const float* c_prev = (const float*)d_in[2];
  const float* w_xi = (const float*)d_in[3];
  const float* w_hi = (const float*)d_in[4];
  const float* w_ci = (const float*)d_in[5];
  const float* w_xf = (const float*)d_in[6];
  const float* w_hf = (const float*)d_in[7];
  const float* w_cf = (const float*)d_in[8];
  const float* w_xg = (const float*)d_in[9];
  const float* w_hg = (const float*)d_in[10];
  const float* w_xo = (const float*)d_in[11];
  const float* w_ho = (const float*)d_in[12];
  const float* w_co = (const float*)d_in[13];
  const float* w_c  = (const float*)d_in[14];
  const float* w_i  = (const float*)d_in[15];
  const float* b_i  = (const float*)d_in[16];
  const float* b_f  = (const float*)d_in[17];
  const float* b_g  = (const float*)d_in[18];
  const float* b_o  = (const float*)d_in[19];

  // workspace layout (bf16 elements): 96,468,992 el = 192.9 MB (same footprint as round 1)
  u16* ws = (u16*)d_ws;
  u16* WtI  = ws;                          // 2048 x 6144  [n][k: xi|hi|ci]
  u16* WtF  = WtI  + (size_t)2048 * 6144;  // 2048 x 6144  [n][k: xf|hf|cf]
  u16* WtG  = WtF  + (size_t)2048 * 6144;  // 2048 x 4096  [n][k: xg|hg]
  u16* WtO  = WtG  + (size_t)2048 * 4096;  // 2048 x 4096  [n][k: xo|ho]
  u16* WtR  = WtO  + (size_t)2048 * 4096;  // 2048 x 2048  [n][k: w_i]
  u16* WtCO = WtR  + (size_t)2048 * 2048;  // 2048 x 2048
  u16* WtC  = WtCO + (size_t)2048 * 2048;  // 2048 x 2048
  u16* zi   = WtC  + (size_t)2048 * 2048;  // [4096 x 2048] bf16 each
  u16* zf   = zi + (size_t)BH;
  u16* zg   = zf + (size_t)BH;
  u16* zo   = zg + (size_t)BH;
  u16* zr   = zo + (size_t)BH;

  // bf16 activation staging lives in d_out (dead space until ew1/ew2 write the real outputs)
  u16* ob16 = (u16*)d_out;
  u16* xb = ob16;                 // bf16(input_)  — overwritten by h (fp32) at the very end
  u16* hb = ob16 + (size_t)BH;    // bf16(h_prev)
  u16* cb = ob16 + (size_t)2 * BH;// bf16(c_prev)  — overwritten by c (fp32) in ew1
  float* out_f = (float*)d_out;
  float* h_out = out_f;           // [0, BH)
  float* c_out = out_f + (size_t)BH;  // [BH, 2BH)

  // 1. activations fp32 -> bf16
  CvtParams cp;
  cp.src[0] = input_; cp.src[1] = h_prev; cp.src[2] = c_prev;
  cp.dst[0] = xb; cp.dst[1] = hb; cp.dst[2] = cb;
  cvt_k<<<dim3(BH / 2048, 3), 256, 0, stream>>>(cp);

  // 2. weights fp32 -> bf16, transposed into fused-K layouts
  TransParams tp;
  const float* srcs[13] = {w_xi, w_hi, w_ci, w_xf, w_hf, w_cf, w_xg, w_hg, w_xo, w_ho, w_i, w_co, w_c};
  u16* dsts[13] = {WtI, WtI + 2048, WtI + 4096, WtF, WtF + 2048, WtF + 4096,
                   WtG, WtG + 2048, WtO, WtO + 2048, WtR, WtCO, WtC};
  int strides[13] = {6144, 6144, 6144, 6144, 6144, 6144, 4096, 4096, 4096, 4096, 2048, 2048, 2048};
  for (int i = 0; i < 13; i++) { tp.src[i] = srcs[i]; tp.dst[i] = dsts[i]; tp.dstride[i] = strides[i]; }
  transpose_k<<<dim3(32, 32, 13), 256, 0, stream>>>(tp);

  // 3. phase-1 GEMMs (fused K; one launch, grid.z = gate)
  GemmParams g1;
  g1.d[0] = {xb, hb, cb, WtI, zi, 3, 0};
  g1.d[1] = {xb, hb, cb, WtF, zf, 3, 0};
  g1.d[2] = {xb, hb, nullptr, WtG, zg, 2, 0};
  g1.d[3] = {xb, hb, nullptr, WtO, zo, 2, 0};
  g1.d[4] = {xb, nullptr, nullptr, WtR, zr, 1, 0};
  gemm_multi<<<dim3(16, 32, 5), 256, 0, stream>>>(g1);

  // 4. elementwise 1: c fp32 -> d_out; bf16(c) -> zi (in-place), bf16(tanh c) -> zg (in-place)
  ew1_k<<<dim3(BH / 2048), 256, 0, stream>>>(zi, zf, zg, c_prev, b_i, b_f, b_g, c_out);

  // 5. phase-3 GEMMs: zo += c @ w_co ; zr += tanh(c) @ w_c   (in-place accumulate)
  GemmParams g2;
  g2.d[0] = {zi, nullptr, nullptr, WtCO, zo, 1, 1};
  g2.d[1] = {zg, nullptr, nullptr, WtC, zr, 1, 1};
  g2.d[2] = g2.d[0]; g2.d[3] = g2.d[0]; g2.d[4] = g2.d[0];
  gemm_multi<<<dim3(16, 32, 2), 256, 0, stream>>>(g2);

  // 6. elementwise 2: h = tanh(zo + b_o) * zr -> d_out
  ew2_k<<<dim3(BH / 2048), 256, 0, stream>>>(zo, zr, b_o, h_out);
}

// Round 3
// 891.744 us; speedup vs baseline: 1.0428x; 1.0428x over previous
//
#include <hip/hip_runtime.h>
#include <cstdint>
#include <cstddef>

typedef unsigned short u16;
typedef __bf16 bf16x8 __attribute__((ext_vector_type(8)));
typedef float f32x4 __attribute__((ext_vector_type(4)));
typedef u16 u16x8 __attribute__((ext_vector_type(8)));

#define B_DIM 4096
#define H_DIM 2048
#define BH 8388608  // B_DIM * H_DIM

__device__ __forceinline__ float b2f(u16 x) {
  union { uint32_t u; float f; } v;
  v.u = ((uint32_t)x) << 16;
  return v.f;
}
__device__ __forceinline__ u16 f2b(float f) {
  union { float f; uint32_t u; } v;
  v.f = f;
  uint32_t r = v.u + 0x7FFFu + ((v.u >> 16) & 1u);
  return (u16)(r >> 16);
}
__device__ __forceinline__ float sigm(float x) { return 1.0f / (1.0f + __expf(-x)); }

typedef __attribute__((address_space(1))) void gv_t;
typedef __attribute__((address_space(3))) void lv_t;
__device__ __forceinline__ void g2lds16(const void* g, void* l) {
  __builtin_amdgcn_global_load_lds((gv_t*)g, (lv_t*)l, 16, 0, 0);
}

// ---------------- fp32 -> bf16 activation convert ----------------
struct CvtParams { const float* src[3]; u16* dst[3]; };

__global__ __launch_bounds__(256) void cvt_k(CvtParams p) {
  const float* __restrict__ s = p.src[blockIdx.y];
  u16* __restrict__ d = p.dst[blockIdx.y];
  size_t idx = ((size_t)blockIdx.x * 256 + threadIdx.x) * 8;
  float4 a = *(const float4*)(s + idx);
  float4 b = *(const float4*)(s + idx + 4);
  u16x8 o;
  o[0] = f2b(a.x); o[1] = f2b(a.y); o[2] = f2b(a.z); o[3] = f2b(a.w);
  o[4] = f2b(b.x); o[5] = f2b(b.y); o[6] = f2b(b.z); o[7] = f2b(b.w);
  *(u16x8*)(d + idx) = o;
}

// ---------------- weight transpose+convert: Wt[n][k] = bf16(W[k][n]) ----------------
struct TransParams {
  const float* src[13];
  u16* dst[13];
  int dstride[13];
};

__global__ __launch_bounds__(256) void transpose_k(TransParams p) {
  __shared__ u16 lds[64][72];  // pitch 72 breaks bank aliasing
  const int mat = blockIdx.z;
  const float* __restrict__ src = p.src[mat];
  u16* __restrict__ dst = p.dst[mat];
  const int dstride = p.dstride[mat];
  const int tk = blockIdx.y * 64;
  const int tn = blockIdx.x * 64;
  const int t = threadIdx.x;
  const int lr = t >> 3;
  const int lc = (t & 7) * 8;
#pragma unroll
  for (int half = 0; half < 2; half++) {
    int r = lr + half * 32;
    const float4* g = (const float4*)(src + (size_t)(tk + r) * 2048 + tn + lc);
    float4 a = g[0], b = g[1];
    u16x8 t8;
    t8[0] = f2b(a.x); t8[1] = f2b(a.y); t8[2] = f2b(a.z); t8[3] = f2b(a.w);
    t8[4] = f2b(b.x); t8[5] = f2b(b.y); t8[6] = f2b(b.z); t8[7] = f2b(b.w);
    *(u16x8*)&lds[r][lc] = t8;
  }
  __syncthreads();
#pragma unroll
  for (int half = 0; half < 2; half++) {
    int n = lr + half * 32;
    u16x8 tmp;
#pragma unroll
    for (int j = 0; j < 8; j++) tmp[j] = lds[lc + j][n];
    *(u16x8*)(dst + (size_t)(tn + n) * dstride + tk + lc) = tmp;
  }
}

// ---------------- shared K=2048 segment: BK=64, XOR-swizzled LDS ----------------
// LDS tile 128 rows x 64 k (bf16), row = 128 B. Chunk (16 B) c of row r stored at
// slot s = c ^ (r & 7)  ->  ds_read_b128 quarter-phases are 2-way (free).
// Staging: lane l writes LDS slot l&7 of row (l>>3); loads global chunk (l&7)^(l>>3).
__device__ __forceinline__ void seg2048(
    const u16* __restrict__ Aseg,   // A + m0*2048 (stride 2048)
    const u16* __restrict__ Wseg,   // Wt + n0*ldW + seg_k_offset (stride ldW)
    long ldW,
    u16* ldsA, u16* ldsB,
    int wave, int lane,
    int wm, int wn, int fm, int fkc,
    f32x4 (&acc)[4][4]) {
  const int sr8 = lane >> 3;            // 0..7: row within 8-row staging group
  const int slot = lane & 7;            // LDS slot (fixed by lane-contiguity)
  const int sc = ((slot ^ sr8) << 3);   // global k-chunk this lane fetches (elems)
  const u16* pA[4]; const u16* pB[4];
  u16* lA[4]; u16* lB[4];
#pragma unroll
  for (int i = 0; i < 4; i++) {
    int rl = wave * 32 + i * 8;
    pA[i] = Aseg + (size_t)(rl + sr8) * 2048 + sc;
    pB[i] = Wseg + (size_t)(rl + sr8) * ldW + sc;
    lA[i] = ldsA + rl * 64;
    lB[i] = ldsB + rl * 64;
  }
  const int x7 = fm & 7;
  int raBase[4], rbBase[4];
#pragma unroll
  for (int i = 0; i < 4; i++) {
    raBase[i] = (wm + i * 16 + fm) * 64;
    rbBase[i] = (wn + i * 16 + fm) * 64;
  }
  for (int it = 0; it < 32; ++it) {
    __syncthreads();  // previous tile's LDS reads done
#pragma unroll
    for (int i = 0; i < 4; i++) { g2lds16(pA[i], lA[i]); g2lds16(pB[i], lB[i]); }
    __syncthreads();  // vmcnt(0) drain: staged data visible
#pragma unroll
    for (int ks = 0; ks < 2; ks++) {
      const int c = ks * 4 + fkc;
      const int so = ((c ^ x7) << 3);
      bf16x8 af[4], bfr[4];
#pragma unroll
      for (int i = 0; i < 4; i++) {
        af[i] = *(const bf16x8*)&ldsA[raBase[i] + so];
        bfr[i] = *(const bf16x8*)&ldsB[rbBase[i] + so];
      }
#pragma unroll
      for (int i = 0; i < 4; i++)
#pragma unroll
        for (int j = 0; j < 4; j++)
          acc[i][j] = __builtin_amdgcn_mfma_f32_16x16x32_bf16(af[i], bfr[j], acc[i][j], 0, 0, 0);
    }
#pragma unroll
    for (int i = 0; i < 4; i++) { pA[i] += 64; pB[i] += 64; }
  }
}

// ---------------- phase-1 GEMM: C[4096,2048](bf16) = sum_seg A_seg @ Wt_seg^T ----------------
struct GemmDesc {
  const u16* A0; const u16* A1; const u16* A2;
  const u16* Wt; u16* C; int nseg;
};
struct GemmParams { GemmDesc d[5]; };

__global__ __launch_bounds__(256) void gemm_multi(GemmParams p) {
  const GemmDesc d = p.d[blockIdx.z];
  const int nseg = d.nseg;
  const long Ktot = (long)nseg * 2048;

  __shared__ u16 ldsA[128 * 64];
  __shared__ u16 ldsB[128 * 64];

  const int t = threadIdx.x;
  const int wave = t >> 6, lane = t & 63;
  const int m0 = blockIdx.y * 128, n0 = blockIdx.x * 128;
  const int fm = lane & 15, fkc = lane >> 4;       // frag row, k-chunk-half (0..3)
  const int wm = (wave >> 1) * 64, wn = (wave & 1) * 64;

  f32x4 acc[4][4];
#pragma unroll
  for (int i = 0; i < 4; i++)
#pragma unroll
    for (int j = 0; j < 4; j++) acc[i][j] = (f32x4)0.0f;

  for (int seg = 0; seg < nseg; ++seg) {
    const u16* As = (seg == 0) ? d.A0 : ((seg == 1) ? d.A1 : d.A2);
    seg2048(As + (size_t)m0 * 2048,
            d.Wt + (size_t)n0 * Ktot + (size_t)seg * 2048, Ktot,
            ldsA, ldsB, wave, lane, wm, wn, fm, fkc, acc);
  }

  // epilogue: C/D layout col=lane&15, row=quad*4+r
  const int quad = lane >> 4;
#pragma unroll
  for (int i = 0; i < 4; i++) {
#pragma unroll
    for (int j = 0; j < 4; j++) {
#pragma unroll
      for (int r = 0; r < 4; r++) {
        size_t row = (size_t)(m0 + wm + i * 16 + quad * 4 + r);
        size_t col = (size_t)(n0 + wn + j * 16 + fm);
        d.C[row * 2048 + col] = f2b(acc[i][j][r]);
      }
    }
  }
}

// ---------------- fused phase-3 + ew2: h = tanh(zo + c@w_co + b_o) * (zr + tanh(c)@w_c) ----
__global__ __launch_bounds__(256) void gemm_res(
    const u16* __restrict__ cb16, const u16* __restrict__ tcb16,
    const u16* __restrict__ WtCO, const u16* __restrict__ WtC,
    const u16* __restrict__ zo, const u16* __restrict__ zr,
    const float* __restrict__ bo, float* __restrict__ h_out) {
  __shared__ u16 ldsA[128 * 64];
  __shared__ u16 ldsB[128 * 64];

  const int t = threadIdx.x;
  const int wave = t >> 6, lane = t & 63;
  const int m0 = blockIdx.y * 128, n0 = blockIdx.x * 128;
  const int fm = lane & 15, fkc = lane >> 4;
  const int wm = (wave >> 1) * 64, wn = (wave & 1) * 64;

  f32x4 acc[4][4];
#pragma unroll
  for (int i = 0; i < 4; i++)
#pragma unroll
    for (int j = 0; j < 4; j++) acc[i][j] = (f32x4)0.0f;

  // t1 = c @ w_co
  seg2048(cb16 + (size_t)m0 * 2048, WtCO + (size_t)n0 * 2048, 2048,
          ldsA, ldsB, wave, lane, wm, wn, fm, fkc, acc);

  // park t1 as packed bf16 pairs (32 VGPRs)
  uint32_t t1p[4][4][2];
#pragma unroll
  for (int i = 0; i < 4; i++)
#pragma unroll
    for (int j = 0; j < 4; j++)
#pragma unroll
      for (int pp = 0; pp < 2; pp++)
        t1p[i][j][pp] = (uint32_t)f2b(acc[i][j][2 * pp]) |
                        ((uint32_t)f2b(acc[i][j][2 * pp + 1]) << 16);

#pragma unroll
  for (int i = 0; i < 4; i++)
#pragma unroll
    for (int j = 0; j < 4; j++) acc[i][j] = (f32x4)0.0f;

  // t2 = tanh(c) @ w_c
  seg2048(tcb16 + (size_t)m0 * 2048, WtC + (size_t)n0 * 2048, 2048,
          ldsA, ldsB, wave, lane, wm, wn, fm, fkc, acc);

  // epilogue: h = tanh(zo + t1 + b_o) * (zr + t2)
  const int quad = lane >> 4;
#pragma unroll
  for (int i = 0; i < 4; i++) {
#pragma unroll
    for (int j = 0; j < 4; j++) {
      int col = n0 + wn + j * 16 + fm;
      float bov = bo[col];
#pragma unroll
      for (int r = 0; r < 4; r++) {
        size_t row = (size_t)(m0 + wm + i * 16 + quad * 4 + r);
        size_t idx = row * 2048 + (size_t)col;
        float t1 = b2f((u16)(t1p[i][j][r >> 1] >> ((r & 1) * 16)));
        float ov = b2f(zo[idx]) + t1 + bov;
        float hv = tanhf(ov) * (b2f(zr[idx]) + acc[i][j][r]);
        h_out[idx] = hv;
      }
    }
  }
}

// ---------------- elementwise 1: gates -> c; stash bf16(c), bf16(tanh c) in-place ----------------
__global__ __launch_bounds__(256) void ew1_k(
    u16* __restrict__ zi, const u16* __restrict__ zf, u16* __restrict__ zg,
    const float* __restrict__ cprev, const float* __restrict__ bi,
    const float* __restrict__ bff, const float* __restrict__ bg,
    float* __restrict__ c_out) {
  size_t idx = ((size_t)blockIdx.x * 256 + threadIdx.x) * 8;
  int col = (int)(idx & (H_DIM - 1));
  u16x8 vzi = *(const u16x8*)(zi + idx);
  u16x8 vzf = *(const u16x8*)(zf + idx);
  u16x8 vzg = *(const u16x8*)(zg + idx);
  float4 cp0 = *(const float4*)(cprev + idx);
  float4 cp1 = *(const float4*)(cprev + idx + 4);
  float4 bi0 = *(const float4*)(bi + col), bi1 = *(const float4*)(bi + col + 4);
  float4 bf0 = *(const float4*)(bff + col), bf1 = *(const float4*)(bff + col + 4);
  float4 bg0 = *(const float4*)(bg + col), bg1 = *(const float4*)(bg + col + 4);
  float cpv[8] = {cp0.x, cp0.y, cp0.z, cp0.w, cp1.x, cp1.y, cp1.z, cp1.w};
  float biv[8] = {bi0.x, bi0.y, bi0.z, bi0.w, bi1.x, bi1.y, bi1.z, bi1.w};
  float bfv[8] = {bf0.x, bf0.y, bf0.z, bf0.w, bf1.x, bf1.y, bf1.z, bf1.w};
  float bgv[8] = {bg0.x, bg0.y, bg0.z, bg0.w, bg1.x, bg1.y, bg1.z, bg1.w};
  float cv[8], tcv[8];
#pragma unroll
  for (int e = 0; e < 8; e++) {
    float iv = b2f(vzi[e]) + biv[e];
    float fv = b2f(vzf[e]) + bfv[e];
    float gv = b2f(vzg[e]) + bgv[e];
    float c = sigm(fv) * cpv[e] + sigm(iv) * tanhf(gv);
    cv[e] = c;
    tcv[e] = tanhf(c);
  }
  u16x8 cb8, tc8;
#pragma unroll
  for (int e = 0; e < 8; e++) { cb8[e] = f2b(cv[e]); tc8[e] = f2b(tcv[e]); }
  *(u16x8*)(zi + idx) = cb8;   // bf16(c) for c @ w_co
  *(u16x8*)(zg + idx) = tc8;   // bf16(tanh c) for tanh(c) @ w_c
  float4 c0 = {cv[0], cv[1], cv[2], cv[3]}, c1 = {cv[4], cv[5], cv[6], cv[7]};
  *(float4*)(c_out + idx) = c0;
  *(float4*)(c_out + idx + 4) = c1;
}

// ---------------- launch ----------------
extern "C" void kernel_launch(void* const* d_in, const int* in_sizes, int n_in,
                              void* d_out, int out_size, void* d_ws, size_t ws_size,
                              hipStream_t stream) {
  const float* input_ = (const float*)d_in[0];
  const float* h_prev = (const float*)d_in[1];
  const float* c_prev = (const float*)d_in[2];
  const float* w_xi = (const float*)d_in[3];
  const float* w_hi = (const float*)d_in[4];
  const float* w_ci = (const float*)d_in[5];
  const float* w_xf = (const float*)d_in[6];
  const float* w_hf = (const float*)d_in[7];
  const float* w_cf = (const float*)d_in[8];
  const float* w_xg = (const float*)d_in[9];
  const float* w_hg = (const float*)d_in[10];
  const float* w_xo = (const float*)d_in[11];
  const float* w_ho = (const float*)d_in[12];
  const float* w_co = (const float*)d_in[13];
  const float* w_c  = (const float*)d_in[14];
  const float* w_i  = (const float*)d_in[15];
  const float* b_i  = (const float*)d_in[16];
  const float* b_f  = (const float*)d_in[17];
  const float* b_g  = (const float*)d_in[18];
  const float* b_o  = (const float*)d_in[19];

  u16* ws = (u16*)d_ws;
  u16* WtI  = ws;                          // 2048 x 6144  [n][k: xi|hi|ci]
  u16* WtF  = WtI  + (size_t)2048 * 6144;
  u16* WtG  = WtF  + (size_t)2048 * 6144;  // 2048 x 4096  [n][k: xg|hg]
  u16* WtO  = WtG  + (size_t)2048 * 4096;
  u16* WtR  = WtO  + (size_t)2048 * 4096;  // 2048 x 2048
  u16* WtCO = WtR  + (size_t)2048 * 2048;
  u16* WtC  = WtCO + (size_t)2048 * 2048;
  u16* zi   = WtC  + (size_t)2048 * 2048;  // [4096 x 2048] bf16 each
  u16* zf   = zi + (size_t)BH;
  u16* zg   = zf + (size_t)BH;
  u16* zo   = zg + (size_t)BH;
  u16* zr   = zo + (size_t)BH;

  u16* ob16 = (u16*)d_out;
  u16* xb = ob16;                  // bf16(input_)  — dead before h written
  u16* hb = ob16 + (size_t)BH;     // bf16(h_prev)
  u16* cb = ob16 + (size_t)2 * BH; // bf16(c_prev)  — dead before c written
  float* out_f = (float*)d_out;
  float* h_out = out_f;
  float* c_out = out_f + (size_t)BH;

  // 1. activations fp32 -> bf16
  CvtParams cp;
  cp.src[0] = input_; cp.src[1] = h_prev; cp.src[2] = c_prev;
  cp.dst[0] = xb; cp.dst[1] = hb; cp.dst[2] = cb;
  cvt_k<<<dim3(BH / 2048, 3), 256, 0, stream>>>(cp);

  // 2. weights fp32 -> bf16, transposed into fused-K layouts
  TransParams tp;
  const float* srcs[13] = {w_xi, w_hi, w_ci, w_xf, w_hf, w_cf, w_xg, w_hg, w_xo, w_ho, w_i, w_co, w_c};
  u16* dsts[13] = {WtI, WtI + 2048, WtI + 4096, WtF, WtF + 2048, WtF + 4096,
                   WtG, WtG + 2048, WtO, WtO + 2048, WtR, WtCO, WtC};
  int strides[13] = {6144, 6144, 6144, 6144, 6144, 6144, 4096, 4096, 4096, 4096, 2048, 2048, 2048};
  for (int i = 0; i < 13; i++) { tp.src[i] = srcs[i]; tp.dst[i] = dsts[i]; tp.dstride[i] = strides[i]; }
  transpose_k<<<dim3(32, 32, 13), 256, 0, stream>>>(tp);

  // 3. phase-1 GEMMs (fused K; one launch, grid.z = gate)
  GemmParams g1;
  g1.d[0] = {xb, hb, cb, WtI, zi, 3};
  g1.d[1] = {xb, hb, cb, WtF, zf, 3};
  g1.d[2] = {xb, hb, nullptr, WtG, zg, 2};
  g1.d[3] = {xb, hb, nullptr, WtO, zo, 2};
  g1.d[4] = {xb, nullptr, nullptr, WtR, zr, 1};
  gemm_multi<<<dim3(16, 32, 5), 256, 0, stream>>>(g1);

  // 4. elementwise 1: c fp32 -> d_out; bf16(c) -> zi, bf16(tanh c) -> zg (in-place)
  ew1_k<<<dim3(BH / 2048), 256, 0, stream>>>(zi, zf, zg, c_prev, b_i, b_f, b_g, c_out);

  // 5. fused phase-3 + ew2: h -> d_out
  gemm_res<<<dim3(16, 32), 256, 0, stream>>>(zi, zg, WtCO, WtC, zo, zr, b_o, h_out);
}